// Round 18
// baseline (84.243 us; speedup 1.0000x reference)
//
#include <hip/hip_runtime.h>

// VQ-VAE vector quantization via bf16-split MFMA, SWAPPED operands,
// Round 18: B-side (codes) read DIRECTLY from L2 into registers.
// No LDS staging, no barriers, no global_load_lds, no vmcnt asm in the
// K-loop: every wave free-runs its own load->MFMA->argmax pipeline and the
// compiler software-pipelines the register loads (counted waits, unroll 2).
// Codebook = 288KB packed, L2-resident per XCD; per-wave re-read = 589MB
// of L2 traffic (~17us pipe time) which now OVERLAPS with the 22us MFMA
// floor instead of serializing behind barriers (r17's convoy).
// A = codes -> lane-local argmax (code id in mantissa low 5 bits per chunk).
// nh folded into GEMM via granule 16/17 (zero C-init).
// ws layout (floats):
//   [0..31]          loss partials
//   [2048..34815]    hist partials 32 x 1024
//   [34816..108543]  packed codes: 16 chunks x 4608 floats (18KB):
//                    [18 granules][64 codes][16B]; g0-7 hi, g8-15 lo,
//                    g16 = [nh0,nh1,nh2,0...], g17 = zeros

typedef __attribute__((ext_vector_type(8))) short short8;
typedef __attribute__((ext_vector_type(16))) float f32x16;

#define LOSS_OFF 0
#define PART_OFF 2048
#define PACKED_OFF 34816
#define NPART 32
#define CHUNK_B 18432

__device__ __forceinline__ unsigned short bf16_rne(float v, float& rest) {
  const unsigned u = __float_as_uint(v);
  const unsigned r = u + 0x7fffu + ((u >> 16) & 1u);
  const unsigned short h = (unsigned short)(r >> 16);
  rest = v - __uint_as_float((unsigned)h << 16);
  return h;
}

__global__ void vq_pack(const float* __restrict__ cb0, const float* __restrict__ cb1,
                        float* __restrict__ ws) {
  const int c = blockIdx.x * 256 + threadIdx.x;  // 0..1023
  if (c < NPART) ws[LOSS_OFF + c] = 0.0f;
#pragma unroll
  for (int p = 0; p < NPART; ++p) ws[PART_OFF + p * 1024 + c] = 0.0f;
  const float* row = (c < 512) ? (cb0 + (size_t)c * 64) : (cb1 + (size_t)(c - 512) * 64);
  float v[64];
  float nrm = 0.f;
#pragma unroll
  for (int d = 0; d < 64; d += 4) {
    const float4 f = *(const float4*)(row + d);
    v[d] = f.x; v[d + 1] = f.y; v[d + 2] = f.z; v[d + 3] = f.w;
    nrm += f.x * f.x + f.y * f.y + f.z * f.z + f.w * f.w;
  }
  unsigned short hi[64], lo[64];
#pragma unroll
  for (int d = 0; d < 64; ++d) {
    float rest, dump;
    hi[d] = bf16_rne(v[d], rest);
    lo[d] = bf16_rne(rest, dump);
  }
  float* base = ws + PACKED_OFF + (size_t)(c >> 6) * 4608 + (c & 63) * 4;
#pragma unroll
  for (int g = 0; g < 16; ++g) {
    short8 gr;
#pragma unroll
    for (int e = 0; e < 8; ++e)
      gr[e] = (short)((g < 8) ? hi[g * 8 + e] : lo[(g - 8) * 8 + e]);
    *(short8*)(base + g * 256) = gr;
  }
  {  // g16 = 3-term bf16 split of -0.5||c||^2 ; g17 = zeros (half-1 k-slice)
    const float nh = -0.5f * nrm;
    float r1, r2, dump;
    const unsigned short n0 = bf16_rne(nh, r1);
    const unsigned short n1 = bf16_rne(r1, r2);
    const unsigned short n2 = bf16_rne(r2, dump);
    short8 g16 = {(short)n0, (short)n1, (short)n2, 0, 0, 0, 0, 0};
    *(short8*)(base + 16 * 256) = g16;
    short8 zz = {0, 0, 0, 0, 0, 0, 0, 0};
    *(short8*)(base + 17 * 256) = zz;
  }
}

__global__ __launch_bounds__(256, 2) void vq_dist(
    const float* __restrict__ xin, const int* __restrict__ idxp,
    const float* __restrict__ cb0, const float* __restrict__ cb1,
    float* __restrict__ out, float* __restrict__ ws) {
  __shared__ int qidxL[256];   // ONLY LDS use (epilogue handoff)
  const int tid = threadIdx.x;
  const int w = tid >> 6;      // wave 0..3, owns q w*64..+63
  const int l = tid & 63;
  const int half = l >> 5;
  const int col = l & 31;      // this lane's q within its 32-col tile
  const int blk = blockIdx.x;  // 512 blocks x 256 q
  const int bb = blk >> 4;
  const int hw0 = (blk & 15) << 8;
  const int nch = (*idxp == 0) ? 8 : 16;

  // ---- x: direct global->reg, B-fragments for 2 q-col-tiles
  short8 xh[2][4], xl[2][4];
  float xx[2];
#pragma unroll
  for (int m = 0; m < 2; ++m) {
    float vv[4][8];
    const float* xb =
        xin + ((size_t)(bb * 64 + half * 8)) * 4096 + hw0 + w * 64 + m * 32 + col;
#pragma unroll
    for (int kf = 0; kf < 4; ++kf)
#pragma unroll
      for (int j = 0; j < 8; ++j)
        vv[kf][j] = xb[((size_t)(kf * 16 + j)) * 4096];
    float s = 0.f;
#pragma unroll
    for (int kf = 0; kf < 4; ++kf)
#pragma unroll
      for (int j = 0; j < 8; ++j) {
        const float v = vv[kf][j];
        float rest, dump;
        xh[m][kf][j] = (short)bf16_rne(v, rest);
        xl[m][kf][j] = (short)bf16_rne(rest, dump);
        s += v * v;
      }
    s += __shfl_xor(s, 32);  // lanes l, l^32: same q, complementary dims
    xx[m] = s;
  }
  // x~ extension fragment for the nh-granule MFMA: k=0..2 = 1.0 (half-0)
  short8 xnh;
#pragma unroll
  for (int j = 0; j < 8; ++j)
    xnh[j] = (short)((half == 0 && j < 3) ? 0x3F80 : 0);
  const f32x16 ZV = (f32x16)0.0f;  // persistent zero C-input

  // best[m][r]: packed score, low 5 mantissa bits = 31-(2*chunk+n); fmax
  // prefers smaller code on near-ties; r identity kept by register position.
  float best[2][16];
#pragma unroll
  for (int m = 0; m < 2; ++m)
#pragma unroll
    for (int r = 0; r < 16; ++r) best[m][r] = -3.4e38f;

  // per-lane base inside a chunk: code tiles at col*16 (n=0) / +512 (n=1),
  // granule picked by +g*1024; lanes 0-31 read half-0 granule, 32-63 half-1.
  const char* pkl = (const char*)(ws + PACKED_OFF) + col * 16 + half * 1024;

#pragma unroll 2
  for (int i = 0; i < nch; ++i) {
    const char* tb0 = pkl + (size_t)i * CHUNK_B;  // codes 0-31 of chunk
    const char* tb1 = tb0 + 512;                  // codes 32-63

    // nh-granule MFMAs initialize the accumulators (C = ZV)
    const short8 An0 = *(const short8*)(tb0 + 16 * 1024);
    const short8 An1 = *(const short8*)(tb1 + 16 * 1024);
    f32x16 a00 = __builtin_amdgcn_mfma_f32_32x32x16_bf16(An0, xnh, ZV, 0, 0, 0);
    f32x16 a01 = __builtin_amdgcn_mfma_f32_32x32x16_bf16(An1, xnh, ZV, 0, 0, 0);
    f32x16 a10 = __builtin_amdgcn_mfma_f32_32x32x16_bf16(An0, xnh, ZV, 0, 0, 0);
    f32x16 a11 = __builtin_amdgcn_mfma_f32_32x32x16_bf16(An1, xnh, ZV, 0, 0, 0);
#pragma unroll
    for (int kf = 0; kf < 4; ++kf) {
      const short8 Ah0 = *(const short8*)(tb0 + (2 * kf) * 1024);
      const short8 Ah1 = *(const short8*)(tb1 + (2 * kf) * 1024);
      const short8 Al0 = *(const short8*)(tb0 + (8 + 2 * kf) * 1024);
      const short8 Al1 = *(const short8*)(tb1 + (8 + 2 * kf) * 1024);
      a00 = __builtin_amdgcn_mfma_f32_32x32x16_bf16(Ah0, xh[0][kf], a00, 0, 0, 0);
      a01 = __builtin_amdgcn_mfma_f32_32x32x16_bf16(Ah1, xh[0][kf], a01, 0, 0, 0);
      a10 = __builtin_amdgcn_mfma_f32_32x32x16_bf16(Ah0, xh[1][kf], a10, 0, 0, 0);
      a11 = __builtin_amdgcn_mfma_f32_32x32x16_bf16(Ah1, xh[1][kf], a11, 0, 0, 0);
      a00 = __builtin_amdgcn_mfma_f32_32x32x16_bf16(Ah0, xl[0][kf], a00, 0, 0, 0);
      a01 = __builtin_amdgcn_mfma_f32_32x32x16_bf16(Ah1, xl[0][kf], a01, 0, 0, 0);
      a10 = __builtin_amdgcn_mfma_f32_32x32x16_bf16(Ah0, xl[1][kf], a10, 0, 0, 0);
      a11 = __builtin_amdgcn_mfma_f32_32x32x16_bf16(Ah1, xl[1][kf], a11, 0, 0, 0);
      a00 = __builtin_amdgcn_mfma_f32_32x32x16_bf16(Al0, xh[0][kf], a00, 0, 0, 0);
      a01 = __builtin_amdgcn_mfma_f32_32x32x16_bf16(Al1, xh[0][kf], a01, 0, 0, 0);
      a10 = __builtin_amdgcn_mfma_f32_32x32x16_bf16(Al0, xh[1][kf], a10, 0, 0, 0);
      a11 = __builtin_amdgcn_mfma_f32_32x32x16_bf16(Al1, xh[1][kf], a11, 0, 0, 0);
    }

    // ---- lane-local running argmax (codes on rows -> per-lane regs)
    const unsigned sid0 = (unsigned)(31 - 2 * i);
    const unsigned sid1 = (unsigned)(30 - 2 * i);
#pragma unroll
    for (int r = 0; r < 16; ++r) {
      const float p00 = __uint_as_float((__float_as_uint(a00[r]) & 0xFFFFFFE0u) | sid0);
      const float p01 = __uint_as_float((__float_as_uint(a01[r]) & 0xFFFFFFE0u) | sid1);
      best[0][r] = fmaxf(fmaxf(p00, p01), best[0][r]);
      const float p10 = __uint_as_float((__float_as_uint(a10[r]) & 0xFFFFFFE0u) | sid0);
      const float p11 = __uint_as_float((__float_as_uint(a11[r]) & 0xFFFFFFE0u) | sid1);
      best[1][r] = fmaxf(fmaxf(p10, p11), best[1][r]);
    }
  }

  // ---- epilogue: per-lane reduce over 16 regs + one cross-half exchange
  float ls = 0.f;
#pragma unroll
  for (int m = 0; m < 2; ++m) {
    float win = best[m][0];
    int wr = 0;
#pragma unroll
    for (int r = 1; r < 16; ++r) {
      const bool g = best[m][r] > win;  // tie -> keep lower r (smaller row)
      win = g ? best[m][r] : win;
      wr = g ? r : wr;
    }
    const unsigned u = __float_as_uint(win);
    const int t = 31 - (int)(u & 31u);
    int code = (t >> 1) * 64 + (t & 1) * 32 + ((wr & 3) + 8 * (wr >> 2) + 4 * half);
    float clean = __uint_as_float(u & 0xFFFFFFE0u);
    const float ocl = __shfl_xor(clean, 32);
    const int oc = __shfl_xor(code, 32);
    const bool take = (ocl > clean) || (ocl == clean && oc < code);
    clean = take ? ocl : clean;
    code = take ? oc : code;
    if (half == 0) {
      qidxL[w * 64 + m * 32 + col] = code;
      ls += xx[m] - 2.0f * clean;  // ||x||^2 - 2(x.c* - 0.5||c*||^2)
    }
  }
#pragma unroll
  for (int mk = 1; mk < 64; mk <<= 1) ls += __shfl_xor(ls, mk);
  if (l == 0) atomicAdd(&ws[LOSS_OFF + (blk & (NPART - 1))], ls);
  __syncthreads();  // qidxL visible to all threads (only block barrier)

  // ---- fused output: histogram partial + gather + NCHW write (coalesced)
  const int ci = qidxL[tid];
  atomicAdd(ws + PART_OFF + (size_t)(blk & (NPART - 1)) * 1024 + ci, 1.0f);
  const float* crow = (ci < 512) ? (cb0 + (size_t)ci * 64) : (cb1 + (size_t)(ci - 512) * 64);
  float* ob = out + (((size_t)(bb * 64)) << 12) + hw0 + tid;
#pragma unroll
  for (int d4 = 0; d4 < 16; ++d4) {
    const float4 f = *(const float4*)(crow + d4 * 4);
    ob[((size_t)(d4 * 4 + 0)) << 12] = f.x;
    ob[((size_t)(d4 * 4 + 1)) << 12] = f.y;
    ob[((size_t)(d4 * 4 + 2)) << 12] = f.z;
    ob[((size_t)(d4 * 4 + 3)) << 12] = f.w;
  }
}

__global__ void vq_final(const float* __restrict__ ws, float* __restrict__ out) {
  __shared__ float sred[256];
  const int t = threadIdx.x;
  float h = 0.f;
#pragma unroll
  for (int i = t; i < 1024; i += 256) {
    float s = 0.f;
#pragma unroll
    for (int p = 0; p < NPART; ++p) s += ws[PART_OFF + p * 1024 + i];
    const float avg = s * (1.0f / 131072.0f);
    h += avg * logf(avg + 1e-10f);
  }
  sred[t] = h;
  __syncthreads();
  for (int s2 = 128; s2 > 0; s2 >>= 1) {
    if (t < s2) sred[t] += sred[t + s2];
    __syncthreads();
  }
  if (t == 0) {
    float lsum = 0.f;
#pragma unroll
    for (int p = 0; p < NPART; ++p) lsum += ws[LOSS_OFF + p];
    out[8388608] = 1.25f * lsum * (1.0f / 8388608.0f);
    out[8388609] = expf(-sred[0]);
  }
}

extern "C" void kernel_launch(void* const* d_in, const int* in_sizes, int n_in,
                              void* d_out, int out_size, void* d_ws, size_t ws_size,
                              hipStream_t stream) {
  (void)in_sizes; (void)n_in; (void)out_size; (void)ws_size;
  const float* xin = (const float*)d_in[0];
  const float* cb0 = (const float*)d_in[1];
  const float* cb1 = (const float*)d_in[2];
  const int* idxp = (const int*)d_in[3];
  float* out = (float*)d_out;
  float* ws = (float*)d_ws;

  vq_pack<<<4, 256, 0, stream>>>(cb0, cb1, ws);
  vq_dist<<<512, 256, 0, stream>>>(xin, idxp, cb0, cb1, out, ws);
  vq_final<<<1, 256, 0, stream>>>(ws, out);
}